// Round 14
// baseline (280.791 us; speedup 1.0000x reference)
//
#include <hip/hip_runtime.h>
#include <math.h>

// ---------------- problem constants ----------------
#define BATCH   256
#define SIGLEN  2048
#define L1OUT   1022   // conv1(2046) -> pool k3 s2
#define L2OUT   339    // conv2(1018) -> pool k3 s3
#define L3OUT   168    // conv3(337)  -> pool k3 s2
#define FCIN    10752  // 64*168

// conv12 tiling: wave = co-tile, 3 pos-tiles, 16x16x32; TP2=16 -> 28.3 KB LDS -> 5 blocks/CU
#define TP2   16
#define NROW  52             // 48 positions + 4 halo
#define H1S   136            // row stride (shorts): 272B rows -> ds_read_b128
#define H1SZ  (NROW*H1S)     // 7072 shorts = 14144 B per plane

// conv3 tiling: 6 tiles of 28 pooled outputs per batch
#define TU3   28

typedef float f32x4  __attribute__((ext_vector_type(4)));
typedef short s16x8  __attribute__((ext_vector_type(8)));

__device__ __forceinline__ unsigned short f2bf(float f) {
    unsigned int u = __float_as_uint(f);
    return (unsigned short)((u + 0x7fffu + ((u >> 16) & 1u)) >> 16);
}
__device__ __forceinline__ float bf2f(unsigned short h) {
    return __uint_as_float(((unsigned int)h) << 16);
}

// ---------------- prep: weight frag splits + fc1 LDS-transpose permute + BN fold + cnt zero ----------------
__launch_bounds__(256)
__global__ void prep_kernel(
    const float* __restrict__ conv1_b,
    const float* __restrict__ g1, const float* __restrict__ b1,
    const float* __restrict__ m1, const float* __restrict__ v1,
    const float* __restrict__ conv2_w, const float* __restrict__ conv2_b,
    const float* __restrict__ g2, const float* __restrict__ b2,
    const float* __restrict__ m2, const float* __restrict__ v2,
    const float* __restrict__ conv3_w, const float* __restrict__ conv3_b,
    const float* __restrict__ g3, const float* __restrict__ b3,
    const float* __restrict__ m3, const float* __restrict__ v3,
    const float* __restrict__ fc1_w,
    unsigned short* __restrict__ w2hi, unsigned short* __restrict__ w2lo,
    unsigned short* __restrict__ w3hi, unsigned short* __restrict__ w3lo,
    float* __restrict__ wp1,
    float* __restrict__ so1, float* __restrict__ so2, float* __restrict__ so3,
    int* __restrict__ cnt)
{
    __shared__ float tl[64 * 169];   // transpose tile, stride 169 breaks conflicts

    int t   = threadIdx.x;
    int tid = blockIdx.x * 256 + t;
    int stride = gridDim.x * 256;

    if (tid < 256) cnt[tid] = 0;

    // fc1 permute via LDS: block o (<48) transposes fc1_w[o] (64co x 168u) -> wp1[o][u*64+co]
    if (blockIdx.x < 48) {
        int o = blockIdx.x;
        for (int i = t; i < FCIN; i += 256) {
            int co = i / L3OUT, u = i - co * L3OUT;
            tl[co * 169 + u] = fc1_w[o * FCIN + i];      // coalesced read
        }
        __syncthreads();
        for (int i = t; i < FCIN; i += 256) {
            int u = i >> 6, co = i & 63;
            wp1[o * FCIN + i] = tl[co * 169 + u];        // coalesced write
        }
    }

    // W2 frag (16x16x32): dst = ((k*4 + ci>>5)*64 + co)*32 + (ci&31)
    for (int i = tid; i < 64*128*5; i += stride) {
        int co = i / 640; int rr = i - co*640; int ci = rr / 5; int k = rr - ci*5;
        float w = conv2_w[i];
        unsigned short hi = f2bf(w);
        unsigned short lo = f2bf(w - bf2f(hi));
        int dst = ((k*4 + (ci >> 5))*64 + co)*32 + (ci & 31);
        w2hi[dst] = hi;
        w2lo[dst] = lo;
    }
    // W3 frag (16x16x32): seg s = k*2 + (ci>>5); dst = (s*64 + co)*32 + (ci&31)
    for (int i = tid; i < 64*64*3; i += stride) {
        int co = i / 192; int r = i - co*192; int ci = r / 3; int k = r - ci*3;
        float w = conv3_w[i];
        unsigned short hi = f2bf(w);
        unsigned short lo = f2bf(w - bf2f(hi));
        int dst = ((k*2 + (ci >> 5))*64 + co)*32 + (ci & 31);
        w3hi[dst] = hi;
        w3lo[dst] = lo;
    }
    if (tid < 128) {
        float s = g1[tid] / sqrtf(v1[tid] + 1e-5f);
        so1[tid]       = s;
        so1[128 + tid] = (conv1_b[tid] - m1[tid]) * s + b1[tid];
    }
    if (tid < 64) {
        float s2 = g2[tid] / sqrtf(v2[tid] + 1e-5f);
        so2[tid]      = s2;
        so2[64 + tid] = (conv2_b[tid] - m2[tid]) * s2 + b2[tid];
        float s3 = g3[tid] / sqrtf(v3[tid] + 1e-5f);
        so3[tid]      = s3;
        so3[64 + tid] = (conv3_b[tid] - m3[tid]) * s3 + b3[tid];
    }
}

// ---------------- fused conv1(fp32) -> conv2 split-bf16 MFMA ----------------
__launch_bounds__(256, 5)
__global__ void conv12_kernel(
    const float* __restrict__ x, const float* __restrict__ w1,
    const unsigned short* __restrict__ w2hi, const unsigned short* __restrict__ w2lo,
    const float* __restrict__ so1, const float* __restrict__ so2,
    unsigned int* __restrict__ h2p)
{
    __shared__ unsigned short h1hi[H1SZ];   // 14144 B; c2 (12480 B) aliases after K-loop
    __shared__ unsigned short h1lo[H1SZ];

    int t  = threadIdx.x;
    int b  = blockIdx.x;
    int u0 = blockIdx.y * TP2;
    int q0 = 3 * u0;
    int wv = __builtin_amdgcn_readfirstlane(t >> 6);
    int l  = t & 63;
    int m  = l & 15;
    int qd = l >> 4;

    // ---- stage 1: conv1 + bn1 + pool + relu, bf16 hi/lo split (13 iters) ----
    float wr[2][9];
    float s1r[2], o1r[2];
    #pragma unroll
    for (int h = 0; h < 2; ++h) {
        int ch = l + 64*h;
        #pragma unroll
        for (int j = 0; j < 9; ++j) wr[h][j] = w1[ch*9 + j];
        s1r[h] = so1[ch]; o1r[h] = so1[128 + ch];
    }
    for (int s = 0; s < 13; ++s) {
        int r = 4*s + wv;   // 0..51
        int xbase = 2*(q0 + r);
        float xv[3][5];
        #pragma unroll
        for (int ci = 0; ci < 3; ++ci) {
            const float* xp = x + (b*3 + ci)*SIGLEN;
            #pragma unroll
            for (int d = 0; d < 5; ++d) {
                int xi = xbase + d; xi = xi < SIGLEN ? xi : SIGLEN - 1;
                xv[ci][d] = xp[xi];
            }
        }
        #pragma unroll
        for (int h = 0; h < 2; ++h) {
            float r0 = 0.f, r1 = 0.f, r2 = 0.f;
            #pragma unroll
            for (int ci = 0; ci < 3; ++ci) {
                float wA = wr[h][ci*3], wB = wr[h][ci*3+1], wC = wr[h][ci*3+2];
                r0 = fmaf(xv[ci][0], wA, fmaf(xv[ci][1], wB, fmaf(xv[ci][2], wC, r0)));
                r1 = fmaf(xv[ci][1], wA, fmaf(xv[ci][2], wB, fmaf(xv[ci][3], wC, r1)));
                r2 = fmaf(xv[ci][2], wA, fmaf(xv[ci][3], wB, fmaf(xv[ci][4], wC, r2)));
            }
            float mx = fmaxf(r0, fmaxf(r1, r2));
            float v  = fmaxf(fmaf(s1r[h], mx, o1r[h]), 0.f);
            unsigned short hi = f2bf(v);
            unsigned short lo = f2bf(v - bf2f(hi));
            h1hi[r*H1S + l + 64*h] = hi;
            h1lo[r*H1S + l + 64*h] = lo;
        }
    }
    __syncthreads();

    // ---- stage 2: 16x16x32 MFMA, wave owns co-tile wv, 3 pos-tiles ----
    f32x4 acc[3] = {(f32x4)(0.f), (f32x4)(0.f), (f32x4)(0.f)};

    const unsigned short* whb = w2hi + wv*512 + m*32 + qd*8;
    const unsigned short* wlb = w2lo + wv*512 + m*32 + qd*8;

    for (int k = 0; k < 5; ++k) {
        #pragma unroll
        for (int cb = 0; cb < 4; ++cb) {
            int st = k*4 + cb;
            s16x8 wh = *(const s16x8*)(whb + st*2048);
            s16x8 wl = *(const s16x8*)(wlb + st*2048);
            #pragma unroll
            for (int pt = 0; pt < 3; ++pt) {
                int row = pt*16 + m + k;   // <= 51
                s16x8 ah = *(const s16x8*)&h1hi[row*H1S + cb*32 + qd*8];
                s16x8 al = *(const s16x8*)&h1lo[row*H1S + cb*32 + qd*8];
                acc[pt] = __builtin_amdgcn_mfma_f32_16x16x32_bf16(ah, wh, acc[pt], 0, 0, 0);
                acc[pt] = __builtin_amdgcn_mfma_f32_16x16x32_bf16(al, wh, acc[pt], 0, 0, 0);
                acc[pt] = __builtin_amdgcn_mfma_f32_16x16x32_bf16(ah, wl, acc[pt], 0, 0, 0);
            }
        }
    }
    __syncthreads();   // all waves done reading h1hi before aliasing as c2

    // D layout: pos = pt*16 + qd*4 + rg, co = wv*16 + m
    float* c2 = (float*)h1hi;   // [48 pos][65]
    #pragma unroll
    for (int pt = 0; pt < 3; ++pt)
        #pragma unroll
        for (int rg = 0; rg < 4; ++rg)
            c2[(pt*16 + qd*4 + rg)*65 + wv*16 + m] = acc[pt][rg];
    __syncthreads();

    // ---- pool(3,3) + bn2 + relu -> h2p[b][u][co] packed bf16 hi|lo ----
    #pragma unroll
    for (int it = 0; it < 4; ++it) {
        int idx = t + it*256;   // < TP2*64 = 1024
        int ul = idx >> 6, co = idx & 63;
        int u = u0 + ul;
        if (u < L2OUT) {
            float v0 = c2[(3*ul  )*65 + co];
            float v1 = c2[(3*ul+1)*65 + co];
            float v2 = c2[(3*ul+2)*65 + co];
            float mm = fmaxf(v0, fmaxf(v1, v2));
            float v  = fmaxf(fmaf(so2[co], mm, so2[64 + co]), 0.f);
            unsigned short hi = f2bf(v);
            unsigned short lo = f2bf(v - bf2f(hi));
            h2p[(b*L2OUT + u)*64 + co] = (unsigned int)hi | ((unsigned int)lo << 16);
        }
    }
}

// ---------------- conv3 MFMA + pool + bn3 + relu + fc1 partial + last-block warp ----------------
// grid (batch, 6 tiles). Partials via device-scope atomicExch; 6th block per batch
// runs fc2/3/4 + tanh + A + CPAB integrate inline (removes warp kernel + drain).
__launch_bounds__(256, 6)
__global__ void conv3fc1_kernel(
    const unsigned int* __restrict__ h2p,
    const unsigned short* __restrict__ w3hi, const unsigned short* __restrict__ w3lo,
    const float* __restrict__ so3, const float* __restrict__ wp1,
    const float* __restrict__ x,
    const float* __restrict__ fc1_b,
    const float* __restrict__ fc2_w, const float* __restrict__ fc2_b,
    const float* __restrict__ fc3_w, const float* __restrict__ fc3_b,
    const float* __restrict__ fc4_w, const float* __restrict__ fc4_b,
    const float* __restrict__ basis,
    float* __restrict__ part, int* __restrict__ cnt,
    float* __restrict__ out)
{
    __shared__ unsigned short h3s[2*66*72];   // 19008 B; c3buf (16640 B) aliases after MFMA
    __shared__ float xs48[48], hl[32], gl[16], thl[5], Al[12];
    __shared__ int flag;

    int t  = threadIdx.x;
    int b  = blockIdx.x;
    int ti = blockIdx.y;
    int u0 = ti * TU3;
    int wv = __builtin_amdgcn_readfirstlane(t >> 6);
    int l  = t & 63;
    int m  = l & 15;
    int qd = l >> 4;

    for (int i = t; i < 66*64; i += 256) {
        int r = i >> 6, ci = i & 63;
        int g = 2*u0 + r; g = g > (L2OUT-1) ? (L2OUT-1) : g;
        unsigned int v = h2p[(b*L2OUT + g)*64 + ci];
        h3s[r*72 + ci]         = (unsigned short)(v & 0xffffu);
        h3s[66*72 + r*72 + ci] = (unsigned short)(v >> 16);
    }
    __syncthreads();

    s16x8 wh[6], wl[6];
    #pragma unroll
    for (int s = 0; s < 6; ++s) {
        wh[s] = *(const s16x8*)(w3hi + s*2048 + (wv*16 + m)*32 + qd*8);
        wl[s] = *(const s16x8*)(w3lo + s*2048 + (wv*16 + m)*32 + qd*8);
    }

    f32x4 acc[4] = {(f32x4)(0.f), (f32x4)(0.f), (f32x4)(0.f), (f32x4)(0.f)};
    #pragma unroll
    for (int pt = 0; pt < 4; ++pt) {
        #pragma unroll
        for (int s = 0; s < 6; ++s) {
            int row = pt*16 + m + (s >> 1);
            int off = (s & 1)*32 + qd*8;
            s16x8 ah = *(const s16x8*)&h3s[row*72 + off];
            s16x8 al = *(const s16x8*)&h3s[66*72 + row*72 + off];
            acc[pt] = __builtin_amdgcn_mfma_f32_16x16x32_bf16(ah, wh[s], acc[pt], 0, 0, 0);
            acc[pt] = __builtin_amdgcn_mfma_f32_16x16x32_bf16(al, wh[s], acc[pt], 0, 0, 0);
            acc[pt] = __builtin_amdgcn_mfma_f32_16x16x32_bf16(ah, wl[s], acc[pt], 0, 0, 0);
        }
    }
    __syncthreads();   // all h3s reads done before aliasing as c3buf

    float* c3buf = (float*)h3s;   // [64 pos][65]
    #pragma unroll
    for (int pt = 0; pt < 4; ++pt)
        #pragma unroll
        for (int rg = 0; rg < 4; ++rg)
            c3buf[(pt*16 + qd*4 + rg)*65 + wv*16 + m] = acc[pt][rg];
    __syncthreads();

    // pooled xs values for co = l, u = u0..u0+27, in registers
    float s3 = so3[l], o3 = so3[64 + l];
    float pooled[TU3];
    #pragma unroll
    for (int u = 0; u < TU3; ++u) {
        int p = 2*u;
        float v0 = c3buf[(p  )*65 + l];
        float v1 = c3buf[(p+1)*65 + l];
        float v2 = c3buf[(p+2)*65 + l];
        pooled[u] = fmaxf(fmaf(s3, fmaxf(v0, fmaxf(v1, v2)), o3), 0.f);
    }

    // fc1 partial: wave wv -> outputs o0..o0+11; lane l = co; weights lane-contiguous.
    int o0 = wv * 12;
    float fa[12];
    #pragma unroll
    for (int j = 0; j < 12; ++j) fa[j] = 0.f;
    #pragma unroll 4
    for (int u = 0; u < TU3; ++u) {
        float pv = pooled[u];
        const float* wp = wp1 + (u0 + u)*64 + l;
        #pragma unroll
        for (int j = 0; j < 12; ++j)
            fa[j] = fmaf(pv, wp[(o0 + j)*FCIN], fa[j]);
    }
    #pragma unroll
    for (int j = 0; j < 12; ++j) {
        #pragma unroll
        for (int off = 32; off > 0; off >>= 1)
            fa[j] += __shfl_xor(fa[j], off, 64);
    }
    if (l == 0) {
        #pragma unroll
        for (int j = 0; j < 12; ++j)
            atomicExch(&part[(b*6 + ti)*48 + o0 + j], fa[j]);   // device-coherent store
    }
    __syncthreads();

    if (t == 0) {
        int old = atomicAdd(&cnt[b], 1);
        flag = (old == 5) ? 1 : 0;
    }
    __syncthreads();
    if (!flag) return;

    // ---- last block for batch b: fc1-reduce + fc2/3/4 + tanh + A ----
    if (t < 48) {
        float sv = 0.f;
        #pragma unroll
        for (int ii = 0; ii < 6; ++ii)
            sv += atomicAdd(&part[(b*6 + ii)*48 + t], 0.0f);    // coherent load
        xs48[t] = fmaxf(sv + fc1_b[t], 0.f);
    }
    __syncthreads();
    if (t < 32) {
        float sv = fc2_b[t];
        #pragma unroll
        for (int k = 0; k < 48; ++k) sv = fmaf(fc2_w[t * 48 + k], xs48[k], sv);
        hl[t] = fmaxf(sv, 0.f);
    }
    __syncthreads();
    if (t < 16) {
        float sv = fc3_b[t];
        #pragma unroll
        for (int k = 0; k < 32; ++k) sv = fmaf(fc3_w[t * 32 + k], hl[k], sv);
        gl[t] = fmaxf(sv, 0.f);
    }
    __syncthreads();
    if (t < 5) {
        float sv = fc4_b[t];
        #pragma unroll
        for (int k = 0; k < 16; ++k) sv = fmaf(fc4_w[t * 16 + k], gl[k], sv);
        thl[t] = tanhf(sv);
    }
    __syncthreads();
    if (t < 12) {
        float sv = 0.f;
        #pragma unroll
        for (int d = 0; d < 5; ++d) sv = fmaf(basis[t * 5 + d], thl[d], sv);
        Al[t] = sv;
    }
    __syncthreads();

    float a_r[6], b_r[6];
    #pragma unroll
    for (int c = 0; c < 6; ++c) { a_r[c] = Al[2*c]; b_r[c] = Al[2*c+1]; }

    // ---- CPAB integrate (7 iters) + interp + transpose, 8 chunks of 256 points ----
    for (int ch = 0; ch < 8; ++ch) {
        int i = ch * 256 + t;
        float xp = (float)i / 2047.f;
        float tt = 1.f;
        for (int it = 0; it < 7; ++it) {
            int c = (int)floorf(xp * 6.f);
            c = min(max(c, 0), 5);
            float a  = a_r[c], bb = b_r[c];
            float v  = a * xp + bb;
            float xb = (v >= 0.f) ? (float)(c + 1) / 6.f : (float)c / 6.f;
            bool  big_a = fabsf(a) > 1e-8f;
            float a_s = big_a ? a : 1.f;
            float z   = xp + bb / a_s;
            float zb  = xb + bb / a_s;
            float zden = (fabsf(z) > 1e-12f) ? z : 1e-12f;
            float ratio = zb / zden;
            float t_exp = logf(fmaxf(ratio, 1e-12f)) / a_s;
            float v_s   = (fabsf(v) > 1e-12f) ? v : 1.f;
            float t_lin = (xb - xp) / v_s;
            float thit  = big_a ? t_exp : t_lin;
            bool valid  = (fabsf(v) > 1e-12f) && (thit > 0.f) && ((big_a ? ratio : 1.f) > 0.f);
            if (!valid) thit = __builtin_inff();
            float tau   = fminf(tt, thit);
            float x_new = big_a ? (z * expf(a * tau) - (z - xp)) : (xp + bb * tau);
            bool hit    = (thit <= tt);
            float nudge = (v >= 0.f) ? 1e-6f : -1e-6f;
            xp = hit ? (xb + nudge) : x_new;
            xp = fminf(fmaxf(xp, 0.f), 1.f);
            tt = fmaxf(tt - tau, 0.f);
        }
        float p = fminf(fmaxf(xp, 0.f), 1.f) * 2047.f;
        int i0 = (int)floorf(p);
        i0 = min(max(i0, 0), 2046);
        float w = p - (float)i0;
        #pragma unroll
        for (int c = 0; c < 3; ++c) {
            const float* d = &x[(b * 3 + c) * SIGLEN];
            out[(b * 3 + c) * SIGLEN + i] = d[i0] * (1.f - w) + d[i0 + 1] * w;
        }
    }
}

// ---------------- launch ----------------
extern "C" void kernel_launch(void* const* d_in, const int* in_sizes, int n_in,
                              void* d_out, int out_size, void* d_ws, size_t ws_size,
                              hipStream_t stream) {
    (void)in_sizes; (void)n_in; (void)out_size; (void)ws_size;
    const float* x       = (const float*)d_in[0];
    const float* conv1_w = (const float*)d_in[1];
    const float* conv1_b = (const float*)d_in[2];
    const float* bn1_g   = (const float*)d_in[3];
    const float* bn1_b   = (const float*)d_in[4];
    const float* bn1_m   = (const float*)d_in[5];
    const float* bn1_v   = (const float*)d_in[6];
    const float* conv2_w = (const float*)d_in[7];
    const float* conv2_b = (const float*)d_in[8];
    const float* bn2_g   = (const float*)d_in[9];
    const float* bn2_b   = (const float*)d_in[10];
    const float* bn2_m   = (const float*)d_in[11];
    const float* bn2_v   = (const float*)d_in[12];
    const float* conv3_w = (const float*)d_in[13];
    const float* conv3_b = (const float*)d_in[14];
    const float* bn3_g   = (const float*)d_in[15];
    const float* bn3_b   = (const float*)d_in[16];
    const float* bn3_m   = (const float*)d_in[17];
    const float* bn3_v   = (const float*)d_in[18];
    const float* fc1_w   = (const float*)d_in[19];
    const float* fc1_b   = (const float*)d_in[20];
    const float* fc2_w   = (const float*)d_in[21];
    const float* fc2_b   = (const float*)d_in[22];
    const float* fc3_w   = (const float*)d_in[23];
    const float* fc3_b   = (const float*)d_in[24];
    const float* fc4_w   = (const float*)d_in[25];
    const float* fc4_b   = (const float*)d_in[26];
    const float* basis   = (const float*)d_in[27];

    // workspace layout
    unsigned short* w2hi = (unsigned short*)d_ws;       // 40960 ush
    unsigned short* w2lo = w2hi + 40960;                // 40960 ush
    unsigned short* w3hi = w2lo + 40960;                // 12288 ush
    unsigned short* w3lo = w3hi + 12288;                // 12288 ush
    float* ws   = (float*)d_ws;
    float* so1  = ws + 53248;           // 256
    float* so2  = so1 + 256;            // 128
    float* so3  = so2 + 128;            // 128
    float* wp1  = so3 + 128;            // 48*10752 = 516096
    unsigned int* h2p = (unsigned int*)(wp1 + 516096);  // 256*339*64 = 5554176 uints
    float* part = (float*)(h2p + 5554176);              // 256*6*48 = 73728
    int*   cnt  = (int*)(part + 73728);                 // 256
    // total ≈ 6.4M elems ≈ 26 MB

    prep_kernel<<<128, 256, 0, stream>>>(
        conv1_b, bn1_g, bn1_b, bn1_m, bn1_v,
        conv2_w, conv2_b, bn2_g, bn2_b, bn2_m, bn2_v,
        conv3_w, conv3_b, bn3_g, bn3_b, bn3_m, bn3_v,
        fc1_w, w2hi, w2lo, w3hi, w3lo, wp1, so1, so2, so3, cnt);

    dim3 g2(BATCH, (L2OUT + TP2 - 1) / TP2);  // (256, 22)
    conv12_kernel<<<g2, 256, 0, stream>>>(x, conv1_w, w2hi, w2lo, so1, so2, h2p);

    dim3 g3(BATCH, 6);  // (256, 6)
    conv3fc1_kernel<<<g3, 256, 0, stream>>>(h2p, w3hi, w3lo, so3, wp1, x,
                                            fc1_b, fc2_w, fc2_b, fc3_w, fc3_b,
                                            fc4_w, fc4_b, basis, part, cnt,
                                            (float*)d_out);
}

// Round 15
// 245.219 us; speedup vs baseline: 1.1451x; 1.1451x over previous
//
#include <hip/hip_runtime.h>
#include <math.h>

// ---------------- problem constants ----------------
#define BATCH   256
#define SIGLEN  2048
#define L1OUT   1022   // conv1(2046) -> pool k3 s2
#define L2OUT   339    // conv2(1018) -> pool k3 s3
#define L3OUT   168    // conv3(337)  -> pool k3 s2
#define FCIN    10752  // 64*168

// conv12 tiling: wave = co-tile, 3 pos-tiles, 16x16x32; TP2=16 -> 28.3 KB LDS -> 5 blocks/CU
#define TP2   16
#define NROW  52             // 48 positions + 4 halo
#define H1S   136            // row stride (shorts): 272B rows -> ds_read_b128
#define H1SZ  (NROW*H1S)     // 7072 shorts = 14144 B per plane

// conv3 tiling: 6 tiles of 28 pooled outputs per batch
#define TU3   28

typedef float f32x4  __attribute__((ext_vector_type(4)));
typedef short s16x8  __attribute__((ext_vector_type(8)));

__device__ __forceinline__ unsigned short f2bf(float f) {
    unsigned int u = __float_as_uint(f);
    return (unsigned short)((u + 0x7fffu + ((u >> 16) & 1u)) >> 16);
}
__device__ __forceinline__ float bf2f(unsigned short h) {
    return __uint_as_float(((unsigned int)h) << 16);
}

// ---------------- prep: weight frag splits + fc1 LDS-transpose permute + BN fold ----------------
__launch_bounds__(256)
__global__ void prep_kernel(
    const float* __restrict__ conv1_b,
    const float* __restrict__ g1, const float* __restrict__ b1,
    const float* __restrict__ m1, const float* __restrict__ v1,
    const float* __restrict__ conv2_w, const float* __restrict__ conv2_b,
    const float* __restrict__ g2, const float* __restrict__ b2,
    const float* __restrict__ m2, const float* __restrict__ v2,
    const float* __restrict__ conv3_w, const float* __restrict__ conv3_b,
    const float* __restrict__ g3, const float* __restrict__ b3,
    const float* __restrict__ m3, const float* __restrict__ v3,
    const float* __restrict__ fc1_w,
    unsigned short* __restrict__ w2hi, unsigned short* __restrict__ w2lo,
    unsigned short* __restrict__ w3hi, unsigned short* __restrict__ w3lo,
    float* __restrict__ wp1,
    float* __restrict__ so1, float* __restrict__ so2, float* __restrict__ so3)
{
    __shared__ float tl[64 * 169];   // transpose tile, stride 169 breaks conflicts

    int t   = threadIdx.x;
    int tid = blockIdx.x * 256 + t;
    int stride = gridDim.x * 256;

    // fc1 permute via LDS: block o (<48) transposes fc1_w[o] (64co x 168u) -> wp1[o][u*64+co]
    if (blockIdx.x < 48) {
        int o = blockIdx.x;
        for (int i = t; i < FCIN; i += 256) {
            int co = i / L3OUT, u = i - co * L3OUT;
            tl[co * 169 + u] = fc1_w[o * FCIN + i];      // coalesced read
        }
        __syncthreads();
        for (int i = t; i < FCIN; i += 256) {
            int u = i >> 6, co = i & 63;
            wp1[o * FCIN + i] = tl[co * 169 + u];        // coalesced write
        }
    }

    // W2 frag (16x16x32): dst = ((k*4 + ci>>5)*64 + co)*32 + (ci&31)
    for (int i = tid; i < 64*128*5; i += stride) {
        int co = i / 640; int rr = i - co*640; int ci = rr / 5; int k = rr - ci*5;
        float w = conv2_w[i];
        unsigned short hi = f2bf(w);
        unsigned short lo = f2bf(w - bf2f(hi));
        int dst = ((k*4 + (ci >> 5))*64 + co)*32 + (ci & 31);
        w2hi[dst] = hi;
        w2lo[dst] = lo;
    }
    // W3 frag (16x16x32): seg s = k*2 + (ci>>5); dst = (s*64 + co)*32 + (ci&31)
    for (int i = tid; i < 64*64*3; i += stride) {
        int co = i / 192; int r = i - co*192; int ci = r / 3; int k = r - ci*3;
        float w = conv3_w[i];
        unsigned short hi = f2bf(w);
        unsigned short lo = f2bf(w - bf2f(hi));
        int dst = ((k*2 + (ci >> 5))*64 + co)*32 + (ci & 31);
        w3hi[dst] = hi;
        w3lo[dst] = lo;
    }
    if (tid < 128) {
        float s = g1[tid] / sqrtf(v1[tid] + 1e-5f);
        so1[tid]       = s;
        so1[128 + tid] = (conv1_b[tid] - m1[tid]) * s + b1[tid];
    }
    if (tid < 64) {
        float s2 = g2[tid] / sqrtf(v2[tid] + 1e-5f);
        so2[tid]      = s2;
        so2[64 + tid] = (conv2_b[tid] - m2[tid]) * s2 + b2[tid];
        float s3 = g3[tid] / sqrtf(v3[tid] + 1e-5f);
        so3[tid]      = s3;
        so3[64 + tid] = (conv3_b[tid] - m3[tid]) * s3 + b3[tid];
    }
}

// ---------------- fused conv1(fp32) -> conv2 split-bf16 MFMA ----------------
// TP2=16: 48 conv positions, 3 pos-tiles/wave, 52 rows. 28.3 KB LDS -> 5 blocks/CU.
// Stage-1 x loads vectorized (2x float2 + 1 scalar) on the wave-uniform fast path.
__launch_bounds__(256, 5)
__global__ void conv12_kernel(
    const float* __restrict__ x, const float* __restrict__ w1,
    const unsigned short* __restrict__ w2hi, const unsigned short* __restrict__ w2lo,
    const float* __restrict__ so1, const float* __restrict__ so2,
    unsigned int* __restrict__ h2p)
{
    __shared__ unsigned short h1hi[H1SZ];   // 14144 B; c2 (12480 B) aliases after K-loop
    __shared__ unsigned short h1lo[H1SZ];

    int t  = threadIdx.x;
    int b  = blockIdx.x;
    int u0 = blockIdx.y * TP2;
    int q0 = 3 * u0;
    int wv = __builtin_amdgcn_readfirstlane(t >> 6);
    int l  = t & 63;
    int m  = l & 15;
    int qd = l >> 4;

    // ---- stage 1: conv1 + bn1 + pool + relu, bf16 hi/lo split (13 iters) ----
    float wr[2][9];
    float s1r[2], o1r[2];
    #pragma unroll
    for (int h = 0; h < 2; ++h) {
        int ch = l + 64*h;
        #pragma unroll
        for (int j = 0; j < 9; ++j) wr[h][j] = w1[ch*9 + j];
        s1r[h] = so1[ch]; o1r[h] = so1[128 + ch];
    }
    for (int s = 0; s < 13; ++s) {
        int r = 4*s + wv;   // 0..51, wave-uniform
        int xbase = 2*(q0 + r);
        float xv[3][5];
        if (xbase + 4 <= SIGLEN - 1) {
            // fast path (wave-uniform): 8B-aligned vector loads, same values as scalar path
            #pragma unroll
            for (int ci = 0; ci < 3; ++ci) {
                const float* xp = x + (b*3 + ci)*SIGLEN + xbase;
                float2 v01 = *(const float2*)(xp);
                float2 v23 = *(const float2*)(xp + 2);
                xv[ci][0] = v01.x; xv[ci][1] = v01.y;
                xv[ci][2] = v23.x; xv[ci][3] = v23.y;
                xv[ci][4] = xp[4];
            }
        } else {
            #pragma unroll
            for (int ci = 0; ci < 3; ++ci) {
                const float* xp = x + (b*3 + ci)*SIGLEN;
                #pragma unroll
                for (int d = 0; d < 5; ++d) {
                    int xi = xbase + d; xi = xi < SIGLEN ? xi : SIGLEN - 1;
                    xv[ci][d] = xp[xi];
                }
            }
        }
        #pragma unroll
        for (int h = 0; h < 2; ++h) {
            float r0 = 0.f, r1 = 0.f, r2 = 0.f;
            #pragma unroll
            for (int ci = 0; ci < 3; ++ci) {
                float wA = wr[h][ci*3], wB = wr[h][ci*3+1], wC = wr[h][ci*3+2];
                r0 = fmaf(xv[ci][0], wA, fmaf(xv[ci][1], wB, fmaf(xv[ci][2], wC, r0)));
                r1 = fmaf(xv[ci][1], wA, fmaf(xv[ci][2], wB, fmaf(xv[ci][3], wC, r1)));
                r2 = fmaf(xv[ci][2], wA, fmaf(xv[ci][3], wB, fmaf(xv[ci][4], wC, r2)));
            }
            float mx = fmaxf(r0, fmaxf(r1, r2));
            float v  = fmaxf(fmaf(s1r[h], mx, o1r[h]), 0.f);
            unsigned short hi = f2bf(v);
            unsigned short lo = f2bf(v - bf2f(hi));
            h1hi[r*H1S + l + 64*h] = hi;
            h1lo[r*H1S + l + 64*h] = lo;
        }
    }
    __syncthreads();

    // ---- stage 2: 16x16x32 MFMA, wave owns co-tile wv, 3 pos-tiles ----
    f32x4 acc[3] = {(f32x4)(0.f), (f32x4)(0.f), (f32x4)(0.f)};

    const unsigned short* whb = w2hi + wv*512 + m*32 + qd*8;
    const unsigned short* wlb = w2lo + wv*512 + m*32 + qd*8;

    for (int k = 0; k < 5; ++k) {
        #pragma unroll
        for (int cb = 0; cb < 4; ++cb) {
            int st = k*4 + cb;
            s16x8 wh = *(const s16x8*)(whb + st*2048);
            s16x8 wl = *(const s16x8*)(wlb + st*2048);
            #pragma unroll
            for (int pt = 0; pt < 3; ++pt) {
                int row = pt*16 + m + k;   // <= 51
                s16x8 ah = *(const s16x8*)&h1hi[row*H1S + cb*32 + qd*8];
                s16x8 al = *(const s16x8*)&h1lo[row*H1S + cb*32 + qd*8];
                acc[pt] = __builtin_amdgcn_mfma_f32_16x16x32_bf16(ah, wh, acc[pt], 0, 0, 0);
                acc[pt] = __builtin_amdgcn_mfma_f32_16x16x32_bf16(al, wh, acc[pt], 0, 0, 0);
                acc[pt] = __builtin_amdgcn_mfma_f32_16x16x32_bf16(ah, wl, acc[pt], 0, 0, 0);
            }
        }
    }
    __syncthreads();   // all waves done reading h1hi before aliasing as c2

    // D layout: pos = pt*16 + qd*4 + rg, co = wv*16 + m
    float* c2 = (float*)h1hi;   // [48 pos][65]
    #pragma unroll
    for (int pt = 0; pt < 3; ++pt)
        #pragma unroll
        for (int rg = 0; rg < 4; ++rg)
            c2[(pt*16 + qd*4 + rg)*65 + wv*16 + m] = acc[pt][rg];
    __syncthreads();

    // ---- pool(3,3) + bn2 + relu -> h2p[b][u][co] packed bf16 hi|lo ----
    #pragma unroll
    for (int it = 0; it < 4; ++it) {
        int idx = t + it*256;   // < TP2*64 = 1024
        int ul = idx >> 6, co = idx & 63;
        int u = u0 + ul;
        if (u < L2OUT) {
            float v0 = c2[(3*ul  )*65 + co];
            float v1 = c2[(3*ul+1)*65 + co];
            float v2 = c2[(3*ul+2)*65 + co];
            float mm = fmaxf(v0, fmaxf(v1, v2));
            float v  = fmaxf(fmaf(so2[co], mm, so2[64 + co]), 0.f);
            unsigned short hi = f2bf(v);
            unsigned short lo = f2bf(v - bf2f(hi));
            h2p[(b*L2OUT + u)*64 + co] = (unsigned int)hi | ((unsigned int)lo << 16);
        }
    }
}

// ---------------- conv3 MFMA + pool + bn3 + relu + fc1 partial (coalesced wp1) ----------------
__launch_bounds__(256, 4)
__global__ void conv3fc1_kernel(
    const unsigned int* __restrict__ h2p,
    const unsigned short* __restrict__ w3hi, const unsigned short* __restrict__ w3lo,
    const float* __restrict__ so3, const float* __restrict__ wp1,
    float* __restrict__ part)
{
    __shared__ unsigned short h3s[2*66*72];   // hi plane | lo plane
    __shared__ float c3buf[64*65];

    int t  = threadIdx.x;
    int b  = blockIdx.x;
    int ti = blockIdx.y;
    int u0 = ti * TU3;
    int wv = __builtin_amdgcn_readfirstlane(t >> 6);
    int l  = t & 63;
    int m  = l & 15;
    int qd = l >> 4;

    for (int i = t; i < 66*64; i += 256) {
        int r = i >> 6, ci = i & 63;
        int g = 2*u0 + r; g = g > (L2OUT-1) ? (L2OUT-1) : g;
        unsigned int v = h2p[(b*L2OUT + g)*64 + ci];
        h3s[r*72 + ci]         = (unsigned short)(v & 0xffffu);
        h3s[66*72 + r*72 + ci] = (unsigned short)(v >> 16);
    }
    __syncthreads();

    s16x8 wh[6], wl[6];
    #pragma unroll
    for (int s = 0; s < 6; ++s) {
        wh[s] = *(const s16x8*)(w3hi + s*2048 + (wv*16 + m)*32 + qd*8);
        wl[s] = *(const s16x8*)(w3lo + s*2048 + (wv*16 + m)*32 + qd*8);
    }

    f32x4 acc[4] = {(f32x4)(0.f), (f32x4)(0.f), (f32x4)(0.f), (f32x4)(0.f)};
    #pragma unroll
    for (int pt = 0; pt < 4; ++pt) {
        #pragma unroll
        for (int s = 0; s < 6; ++s) {
            int row = pt*16 + m + (s >> 1);
            int off = (s & 1)*32 + qd*8;
            s16x8 ah = *(const s16x8*)&h3s[row*72 + off];
            s16x8 al = *(const s16x8*)&h3s[66*72 + row*72 + off];
            acc[pt] = __builtin_amdgcn_mfma_f32_16x16x32_bf16(ah, wh[s], acc[pt], 0, 0, 0);
            acc[pt] = __builtin_amdgcn_mfma_f32_16x16x32_bf16(al, wh[s], acc[pt], 0, 0, 0);
            acc[pt] = __builtin_amdgcn_mfma_f32_16x16x32_bf16(ah, wl[s], acc[pt], 0, 0, 0);
        }
    }
    __syncthreads();

    #pragma unroll
    for (int pt = 0; pt < 4; ++pt)
        #pragma unroll
        for (int rg = 0; rg < 4; ++rg)
            c3buf[(pt*16 + qd*4 + rg)*65 + wv*16 + m] = acc[pt][rg];
    __syncthreads();

    // pooled xs values for co = l, u = u0..u0+27, in registers
    float s3 = so3[l], o3 = so3[64 + l];
    float pooled[TU3];
    #pragma unroll
    for (int u = 0; u < TU3; ++u) {
        int p = 2*u;
        float v0 = c3buf[(p  )*65 + l];
        float v1 = c3buf[(p+1)*65 + l];
        float v2 = c3buf[(p+2)*65 + l];
        pooled[u] = fmaxf(fmaf(s3, fmaxf(v0, fmaxf(v1, v2)), o3), 0.f);
    }

    // fc1 partial: wave wv -> outputs o0..o0+11; lane l = co; weights lane-contiguous.
    int o0 = wv * 12;
    float fa[12];
    #pragma unroll
    for (int j = 0; j < 12; ++j) fa[j] = 0.f;
    #pragma unroll 4
    for (int u = 0; u < TU3; ++u) {
        float pv = pooled[u];
        const float* wp = wp1 + (u0 + u)*64 + l;
        #pragma unroll
        for (int j = 0; j < 12; ++j)
            fa[j] = fmaf(pv, wp[(o0 + j)*FCIN], fa[j]);
    }
    #pragma unroll
    for (int j = 0; j < 12; ++j) {
        #pragma unroll
        for (int off = 32; off > 0; off >>= 1)
            fa[j] += __shfl_xor(fa[j], off, 64);
    }
    if (l == 0) {
        #pragma unroll
        for (int j = 0; j < 12; ++j)
            part[(b*6 + ti)*48 + o0 + j] = fa[j];
    }
}

// ---------------- warp: fc1-reduce + fc2/3/4 + tanh + A, then 2 chunks of points ----------------
__launch_bounds__(256)
__global__ void warp_kernel(
    const float* __restrict__ x, const float* __restrict__ part,
    const float* __restrict__ fc1_b,
    const float* __restrict__ fc2_w, const float* __restrict__ fc2_b,
    const float* __restrict__ fc3_w, const float* __restrict__ fc3_b,
    const float* __restrict__ fc4_w, const float* __restrict__ fc4_b,
    const float* __restrict__ basis,
    float* __restrict__ out)
{
    __shared__ float xs48[48], hl[32], gl[16], thl[5], Al[12];

    int b = blockIdx.x;
    int t = threadIdx.x;

    if (t < 48) {
        float sv = 0.f;
        #pragma unroll
        for (int ti = 0; ti < 6; ++ti) sv += part[(b*6 + ti)*48 + t];
        xs48[t] = fmaxf(sv + fc1_b[t], 0.f);
    }
    __syncthreads();
    if (t < 32) {
        float sv = fc2_b[t];
        #pragma unroll
        for (int k = 0; k < 48; ++k) sv = fmaf(fc2_w[t * 48 + k], xs48[k], sv);
        hl[t] = fmaxf(sv, 0.f);
    }
    __syncthreads();
    if (t < 16) {
        float sv = fc3_b[t];
        #pragma unroll
        for (int k = 0; k < 32; ++k) sv = fmaf(fc3_w[t * 32 + k], hl[k], sv);
        gl[t] = fmaxf(sv, 0.f);
    }
    __syncthreads();
    if (t < 5) {
        float sv = fc4_b[t];
        #pragma unroll
        for (int k = 0; k < 16; ++k) sv = fmaf(fc4_w[t * 16 + k], gl[k], sv);
        thl[t] = tanhf(sv);
    }
    __syncthreads();
    if (t < 12) {
        float sv = 0.f;
        #pragma unroll
        for (int d = 0; d < 5; ++d) sv = fmaf(basis[t * 5 + d], thl[d], sv);
        Al[t] = sv;
    }
    __syncthreads();

    float a_r[6], b_r[6];
    #pragma unroll
    for (int c = 0; c < 6; ++c) { a_r[c] = Al[2*c]; b_r[c] = Al[2*c+1]; }

    #pragma unroll
    for (int cc = 0; cc < 2; ++cc) {
        int i = (blockIdx.y * 2 + cc) * 256 + t;
        float xp = (float)i / 2047.f;
        float tt = 1.f;
        for (int it = 0; it < 7; ++it) {
            int c = (int)floorf(xp * 6.f);
            c = min(max(c, 0), 5);
            float a  = a_r[c], bb = b_r[c];
            float v  = a * xp + bb;
            float xb = (v >= 0.f) ? (float)(c + 1) / 6.f : (float)c / 6.f;
            bool  big_a = fabsf(a) > 1e-8f;
            float a_s = big_a ? a : 1.f;
            float z   = xp + bb / a_s;
            float zb  = xb + bb / a_s;
            float zden = (fabsf(z) > 1e-12f) ? z : 1e-12f;
            float ratio = zb / zden;
            float t_exp = logf(fmaxf(ratio, 1e-12f)) / a_s;
            float v_s   = (fabsf(v) > 1e-12f) ? v : 1.f;
            float t_lin = (xb - xp) / v_s;
            float thit  = big_a ? t_exp : t_lin;
            bool valid  = (fabsf(v) > 1e-12f) && (thit > 0.f) && ((big_a ? ratio : 1.f) > 0.f);
            if (!valid) thit = __builtin_inff();
            float tau   = fminf(tt, thit);
            float x_new = big_a ? (z * expf(a * tau) - (z - xp)) : (xp + bb * tau);
            bool hit    = (thit <= tt);
            float nudge = (v >= 0.f) ? 1e-6f : -1e-6f;
            xp = hit ? (xb + nudge) : x_new;
            xp = fminf(fmaxf(xp, 0.f), 1.f);
            tt = fmaxf(tt - tau, 0.f);
        }
        float p = fminf(fmaxf(xp, 0.f), 1.f) * 2047.f;
        int i0 = (int)floorf(p);
        i0 = min(max(i0, 0), 2046);
        float w = p - (float)i0;
        #pragma unroll
        for (int c = 0; c < 3; ++c) {
            const float* d = &x[(b * 3 + c) * SIGLEN];
            out[(b * 3 + c) * SIGLEN + i] = d[i0] * (1.f - w) + d[i0 + 1] * w;
        }
    }
}

// ---------------- launch ----------------
extern "C" void kernel_launch(void* const* d_in, const int* in_sizes, int n_in,
                              void* d_out, int out_size, void* d_ws, size_t ws_size,
                              hipStream_t stream) {
    (void)in_sizes; (void)n_in; (void)out_size; (void)ws_size;
    const float* x       = (const float*)d_in[0];
    const float* conv1_w = (const float*)d_in[1];
    const float* conv1_b = (const float*)d_in[2];
    const float* bn1_g   = (const float*)d_in[3];
    const float* bn1_b   = (const float*)d_in[4];
    const float* bn1_m   = (const float*)d_in[5];
    const float* bn1_v   = (const float*)d_in[6];
    const float* conv2_w = (const float*)d_in[7];
    const float* conv2_b = (const float*)d_in[8];
    const float* bn2_g   = (const float*)d_in[9];
    const float* bn2_b   = (const float*)d_in[10];
    const float* bn2_m   = (const float*)d_in[11];
    const float* bn2_v   = (const float*)d_in[12];
    const float* conv3_w = (const float*)d_in[13];
    const float* conv3_b = (const float*)d_in[14];
    const float* bn3_g   = (const float*)d_in[15];
    const float* bn3_b   = (const float*)d_in[16];
    const float* bn3_m   = (const float*)d_in[17];
    const float* bn3_v   = (const float*)d_in[18];
    const float* fc1_w   = (const float*)d_in[19];
    const float* fc1_b   = (const float*)d_in[20];
    const float* fc2_w   = (const float*)d_in[21];
    const float* fc2_b   = (const float*)d_in[22];
    const float* fc3_w   = (const float*)d_in[23];
    const float* fc3_b   = (const float*)d_in[24];
    const float* fc4_w   = (const float*)d_in[25];
    const float* fc4_b   = (const float*)d_in[26];
    const float* basis   = (const float*)d_in[27];

    // workspace layout
    unsigned short* w2hi = (unsigned short*)d_ws;       // 40960 ush
    unsigned short* w2lo = w2hi + 40960;                // 40960 ush
    unsigned short* w3hi = w2lo + 40960;                // 12288 ush
    unsigned short* w3lo = w3hi + 12288;                // 12288 ush
    float* ws   = (float*)d_ws;
    float* so1  = ws + 53248;           // 256
    float* so2  = so1 + 256;            // 128
    float* so3  = so2 + 128;            // 128
    float* wp1  = so3 + 128;            // 48*10752 = 516096
    unsigned int* h2p = (unsigned int*)(wp1 + 516096);  // 256*339*64 = 5554176 uints
    float* part = (float*)(h2p + 5554176);              // 256*6*48 = 73728
    // total ≈ 6.4M elems ≈ 26 MB

    prep_kernel<<<128, 256, 0, stream>>>(
        conv1_b, bn1_g, bn1_b, bn1_m, bn1_v,
        conv2_w, conv2_b, bn2_g, bn2_b, bn2_m, bn2_v,
        conv3_w, conv3_b, bn3_g, bn3_b, bn3_m, bn3_v,
        fc1_w, w2hi, w2lo, w3hi, w3lo, wp1, so1, so2, so3);

    dim3 g2(BATCH, (L2OUT + TP2 - 1) / TP2);  // (256, 22)
    conv12_kernel<<<g2, 256, 0, stream>>>(x, conv1_w, w2hi, w2lo, so1, so2, h2p);

    dim3 g3(BATCH, 6);  // (256, 6)
    conv3fc1_kernel<<<g3, 256, 0, stream>>>(h2p, w3hi, w3lo, so3, wp1, part);

    dim3 g5(BATCH, 4);  // (256, 4)
    warp_kernel<<<g5, 256, 0, stream>>>(x, part, fc1_b, fc2_w, fc2_b,
                                        fc3_w, fc3_b, fc4_w, fc4_b, basis,
                                        (float*)d_out);
}